// Round 9
// baseline (324.790 us; speedup 1.0000x reference)
//
#include <hip/hip_runtime.h>
#include <hip/hip_bf16.h>

typedef __bf16 bf16_t;
typedef __bf16 bf16x8 __attribute__((ext_vector_type(8)));
typedef __bf16 bf16x4 __attribute__((ext_vector_type(4)));
typedef float f32x4 __attribute__((ext_vector_type(4)));
typedef signed char i8x4 __attribute__((ext_vector_type(4)));
typedef signed char i8x8 __attribute__((ext_vector_type(8)));

#define NN 50000
#define NE 600000

__device__ __forceinline__ void gload_lds16(const void* g, void* l) {
    __builtin_amdgcn_global_load_lds(
        (const __attribute__((address_space(1))) void*)g,
        (__attribute__((address_space(3))) void*)l, 16, 0, 0);
}

// ---------- fused: x->bf16+int8, weights, deg_count atomics ----------
// blocks [0,6250): x rows (8 rows/block, half-wave per row)
// blocks [6250,6466): weight conversion
// blocks [6466,8810): deg_count atomics (degi pre-zeroed by memset)
__global__ void cvt_all(const float* __restrict__ x, bf16_t* __restrict__ xB,
                        signed char* __restrict__ xQ, float* __restrict__ xScale,
                        const float* __restrict__ Wl1, const float* __restrict__ Wr1,
                        const float* __restrict__ Wl2, const float* __restrict__ Wr2,
                        const float* __restrict__ Wl3, const float* __restrict__ Wr3,
                        bf16_t* __restrict__ o1l, bf16_t* __restrict__ o1r,
                        bf16_t* __restrict__ o2l, bf16_t* __restrict__ o2r,
                        bf16_t* __restrict__ o3, const int* __restrict__ ei,
                        int* __restrict__ degi) {
    int b = blockIdx.x;
    if (b < 6250) {
        int hw = threadIdx.x >> 5, sub = threadIdx.x & 31;
        int row = b * 8 + hw;  // 6250*8 == 50000 exactly
        float4 v = *(const float4*)(x + (long)row * 128 + sub * 4);
        bf16x4 o;
        o[0] = (bf16_t)v.x; o[1] = (bf16_t)v.y; o[2] = (bf16_t)v.z; o[3] = (bf16_t)v.w;
        *(bf16x4*)(xB + (long)row * 128 + sub * 4) = o;
        float m = fmaxf(fmaxf(fabsf(v.x), fabsf(v.y)), fmaxf(fabsf(v.z), fabsf(v.w)));
#pragma unroll
        for (int o2 = 1; o2 < 32; o2 <<= 1) m = fmaxf(m, __shfl_xor(m, o2));
        float rs = m > 0.f ? 127.f / m : 0.f;
        i8x4 q;
        q[0] = (signed char)fminf(fmaxf(rintf(v.x * rs), -127.f), 127.f);
        q[1] = (signed char)fminf(fmaxf(rintf(v.y * rs), -127.f), 127.f);
        q[2] = (signed char)fminf(fmaxf(rintf(v.z * rs), -127.f), 127.f);
        q[3] = (signed char)fminf(fmaxf(rintf(v.w * rs), -127.f), 127.f);
        *(i8x4*)(xQ + (long)row * 128 + sub * 4) = q;
        if (sub == 0) xScale[row] = m * (1.f / 127.f);
    } else if (b < 6466) {
        int t = (b - 6250) * 256 + threadIdx.x;  // [0, 55296)
        bf16x4 o;
        if (t < 49152) {
            const float* in; bf16_t* out; int g;
            if (t < 8192)       { in = Wl1; out = o1l; g = t; }
            else if (t < 16384) { in = Wr1; out = o1r; g = t - 8192; }
            else if (t < 32768) { in = Wl2; out = o2l; g = t - 16384; }
            else                { in = Wr2; out = o2r; g = t - 32768; }
            float4 v = ((const float4*)in)[g];
            o[0] = (bf16_t)v.x; o[1] = (bf16_t)v.y; o[2] = (bf16_t)v.z; o[3] = (bf16_t)v.w;
            ((bf16x4*)out)[g] = o;
        } else if (t < 55296) {
            int g = t - 49152;
            int row = g >> 6, c4 = (g & 63) * 4;  // row in [0,96)
            const float* src = nullptr;
            int srow = 0;
            if (row < 47) { src = Wl3; srow = row; }
            else if (row >= 48 && row < 95) { src = Wr3; srow = row - 48; }
            if (src) {
                float4 v = *(const float4*)(src + srow * 256 + c4);
                o[0] = (bf16_t)v.x; o[1] = (bf16_t)v.y; o[2] = (bf16_t)v.z; o[3] = (bf16_t)v.w;
            } else {
                o[0] = o[1] = o[2] = o[3] = (bf16_t)0.f;
            }
            *(bf16x4*)(o3 + row * 256 + c4) = o;
        }
    } else {
        int e = (b - 6466) * 256 + threadIdx.x;
        if (e < NE) atomicAdd(&degi[ei[NE + e]], 1);
    }
}

// ---------- CSR build ----------
__global__ __launch_bounds__(1024) void scan_blocks(const int* __restrict__ degi,
                                                    int* __restrict__ rowptr,
                                                    float* __restrict__ dinv,
                                                    int* __restrict__ partials, int n) {
    int i = blockIdx.x * 1024 + threadIdx.x;
    int v = (i < n) ? degi[i] : 0;
    int lane = threadIdx.x & 63;
    int w = threadIdx.x >> 6;
    int s = v;
#pragma unroll
    for (int o = 1; o < 64; o <<= 1) {
        int t = __shfl_up(s, o);
        if (lane >= o) s += t;
    }
    __shared__ int wsum[16];
    if (lane == 63) wsum[w] = s;
    __syncthreads();
    if (threadIdx.x < 16) {
        int t = wsum[threadIdx.x];
#pragma unroll
        for (int o = 1; o < 16; o <<= 1) {
            int u = __shfl_up(t, o);
            if ((int)threadIdx.x >= o) t += u;
        }
        wsum[threadIdx.x] = t;
    }
    __syncthreads();
    int incl = s + ((w > 0) ? wsum[w - 1] : 0);
    if (i < n) {
        rowptr[i] = incl - v;
        dinv[i] = 1.0f / fmaxf((float)v, 1.0f);
    }
    if (threadIdx.x == 1023) partials[blockIdx.x] = incl;
}

__global__ void add_offsets(int* __restrict__ rowptr, int* __restrict__ cursor,
                            const int* __restrict__ partials, int nb, int n) {
    __shared__ int bofs[64];
    __shared__ int total_s;
    if (threadIdx.x < 64) {
        int lane = threadIdx.x;
        int v = (lane < nb) ? partials[lane] : 0;
        int s = v;
#pragma unroll
        for (int o = 1; o < 64; o <<= 1) {
            int t = __shfl_up(s, o);
            if (lane >= o) s += t;
        }
        bofs[lane] = s - v;
        if (lane == nb - 1) total_s = s;
    }
    __syncthreads();
    int i = blockIdx.x * blockDim.x + threadIdx.x;
    if (i < n) {
        int v = rowptr[i] + bofs[i >> 10];
        rowptr[i] = v;
        cursor[i] = v;
    }
    if (blockIdx.x == 0 && threadIdx.x == 0) rowptr[n] = total_s;
}

__global__ void fill_csr(const int* __restrict__ ei, int* __restrict__ cursor,
                         int* __restrict__ csr_src, int E) {
    int e = blockIdx.x * blockDim.x + threadIdx.x;
    if (e >= E) return;
    int d = ei[E + e];
    int pos = atomicAdd(&cursor[d], 1);
    csr_src[pos] = ei[e];
}

// ---------- gather aggregations (half-wave per dst node, int8 source) ----------
__global__ void gather_agg_128(const int* __restrict__ rowptr, const int* __restrict__ csr_src,
                               const signed char* __restrict__ Xq, const float* __restrict__ xScale,
                               const float* __restrict__ dinv, bf16_t* __restrict__ out, int N) {
    int wv = blockIdx.x * (blockDim.x >> 6) + (threadIdx.x >> 6);
    int lane = threadIdx.x & 63;
    int node = wv * 2 + (lane >> 5);
    if (node >= N) return;
    int sub = lane & 31;
    int c = sub * 4;
    int s0 = rowptr[node], s1 = rowptr[node + 1];
    float acc[4] = {0.f, 0.f, 0.f, 0.f};
    int j = s0;
    for (; j + 1 < s1; j += 2) {
        int sa = csr_src[j], sb = csr_src[j + 1];
        float fa = xScale[sa], fb = xScale[sb];
        i8x4 va = *(const i8x4*)(Xq + (long)sa * 128 + c);
        i8x4 vb = *(const i8x4*)(Xq + (long)sb * 128 + c);
#pragma unroll
        for (int i = 0; i < 4; i++) acc[i] += fa * (float)va[i] + fb * (float)vb[i];
    }
    if (j < s1) {
        int sa = csr_src[j];
        float fa = xScale[sa];
        i8x4 va = *(const i8x4*)(Xq + (long)sa * 128 + c);
#pragma unroll
        for (int i = 0; i < 4; i++) acc[i] += fa * (float)va[i];
    }
    float di = dinv[node];
    bf16x4 o;
#pragma unroll
    for (int i = 0; i < 4; i++) o[i] = (bf16_t)(acc[i] * di);
    *(bf16x4*)(out + (long)node * 128 + c) = o;
}

// C=256 int8 rows; per-(row,half) scales: hScale[2*row + (sub>=16)]
__global__ void gather_agg_256(const int* __restrict__ rowptr, const int* __restrict__ csr_src,
                               const signed char* __restrict__ Hq, const float* __restrict__ hScale,
                               const float* __restrict__ dinv, bf16_t* __restrict__ out, int N) {
    int wv = blockIdx.x * (blockDim.x >> 6) + (threadIdx.x >> 6);
    int lane = threadIdx.x & 63;
    int node = wv * 2 + (lane >> 5);
    if (node >= N) return;
    int sub = lane & 31;
    int c = sub * 8;
    int half = sub >> 4;
    int s0 = rowptr[node], s1 = rowptr[node + 1];
    float acc[8] = {0.f, 0.f, 0.f, 0.f, 0.f, 0.f, 0.f, 0.f};
    int j = s0;
    for (; j + 1 < s1; j += 2) {
        int sa = csr_src[j], sb = csr_src[j + 1];
        float fa = hScale[sa * 2 + half], fb = hScale[sb * 2 + half];
        i8x8 va = *(const i8x8*)(Hq + (long)sa * 256 + c);
        i8x8 vb = *(const i8x8*)(Hq + (long)sb * 256 + c);
#pragma unroll
        for (int i = 0; i < 8; i++) acc[i] += fa * (float)va[i] + fb * (float)vb[i];
    }
    if (j < s1) {
        int sa = csr_src[j];
        float fa = hScale[sa * 2 + half];
        i8x8 va = *(const i8x8*)(Hq + (long)sa * 256 + c);
#pragma unroll
        for (int i = 0; i < 8; i++) acc[i] += fa * (float)va[i];
    }
    float di = dinv[node];
    bf16x8 o;
#pragma unroll
    for (int i = 0; i < 8; i++) o[i] = (bf16_t)(acc[i] * di);
    *(bf16x8*)(out + (long)node * 256 + c) = o;
}

// ---------- LDS-staged MFMA GEMM: 128x128 tile, BK=64; optional fused int8 quant ----------
// QUANT: also emit per-(row, 128-col-half) int8 (Hq, stride 256) + hScale[2*row+half].
template <int KTOT, bool DUAL, bool RELU, bool QUANT>
__global__ __launch_bounds__(256) void gemm_lds(
    const bf16_t* __restrict__ A1, const bf16_t* __restrict__ A2,
    const bf16_t* __restrict__ W1, const bf16_t* __restrict__ W2,
    bf16_t* __restrict__ Out, int N, int NOUT,
    signed char* __restrict__ Hq, float* __restrict__ hScale) {
    __shared__ bf16_t As[128 * 64];
    __shared__ bf16_t Bs[128 * 64];
    __shared__ float sMax[2][2][64];
    int tid = threadIdx.x;
    int w = tid >> 6, lane = tid & 63;
    int wr = w >> 1, wc = w & 1;
    int rowBase = blockIdx.x * 128;
    int colBase = blockIdx.y * 128;
    int m = lane & 15, q = lane >> 4;

    long aoff[4], boff[4];
    int ldsOff[4];
#pragma unroll
    for (int i = 0; i < 4; i++) {
        int c = w * 256 + i * 64 + lane;
        int r = c >> 3, s = c & 7;
        int gk = (s ^ (r & 7)) << 3;
        aoff[i] = (long)min(rowBase + r, N - 1) * KTOT + gk;
        boff[i] = (long)(colBase + r) * KTOT + gk;
        ldsOff[i] = (w * 4 + i) * 512;
    }

    f32x4 acc[4][4];
#pragma unroll
    for (int a = 0; a < 4; a++)
#pragma unroll
        for (int b = 0; b < 4; b++) acc[a][b] = (f32x4){0.f, 0.f, 0.f, 0.f};

#pragma unroll
    for (int half = 0; half < (DUAL ? 2 : 1); half++) {
        const bf16_t* A = half ? A2 : A1;
        const bf16_t* W = half ? W2 : W1;
#pragma unroll
        for (int k0 = 0; k0 < KTOT; k0 += 64) {
            __syncthreads();
#pragma unroll
            for (int i = 0; i < 4; i++) {
                gload_lds16(A + aoff[i] + k0, As + ldsOff[i]);
                gload_lds16(W + boff[i] + k0, Bs + ldsOff[i]);
            }
            __syncthreads();
#pragma unroll
            for (int ks = 0; ks < 2; ks++) {
                bf16x8 af[4], bfr[4];
#pragma unroll
                for (int rf = 0; rf < 4; rf++) {
                    int r = wr * 64 + rf * 16 + m;
                    int seg = ks * 4 + q;
                    af[rf] = *(const bf16x8*)(As + r * 64 + ((seg ^ (r & 7)) << 3));
                }
#pragma unroll
                for (int cf = 0; cf < 4; cf++) {
                    int r = wc * 64 + cf * 16 + m;
                    int seg = ks * 4 + q;
                    bfr[cf] = *(const bf16x8*)(Bs + r * 64 + ((seg ^ (r & 7)) << 3));
                }
#pragma unroll
                for (int rf = 0; rf < 4; rf++)
#pragma unroll
                    for (int cf = 0; cf < 4; cf++)
                        acc[rf][cf] = __builtin_amdgcn_mfma_f32_16x16x32_bf16(af[rf], bfr[cf], acc[rf][cf], 0, 0, 0);
            }
        }
    }

    int r0 = q * 4;
    if constexpr (QUANT) {
        // per-row max over this block's 128 cols (values are post-relu, >= 0)
        float mm[4][4];
#pragma unroll
        for (int rf = 0; rf < 4; rf++)
#pragma unroll
            for (int i = 0; i < 4; i++) {
                float t = 0.f;
#pragma unroll
                for (int cf = 0; cf < 4; cf++) t = fmaxf(t, fmaxf(acc[rf][cf][i], 0.f));
                mm[rf][i] = t;
            }
#pragma unroll
        for (int o = 1; o < 16; o <<= 1)
#pragma unroll
            for (int rf = 0; rf < 4; rf++)
#pragma unroll
                for (int i = 0; i < 4; i++) mm[rf][i] = fmaxf(mm[rf][i], __shfl_xor(mm[rf][i], o));
        __syncthreads();  // As/Bs done; reuse LDS barrier before sMax writes
        if (m == 0) {
#pragma unroll
            for (int rf = 0; rf < 4; rf++)
#pragma unroll
                for (int i = 0; i < 4; i++) sMax[wr][wc][rf * 16 + q * 4 + i] = mm[rf][i];
        }
        __syncthreads();
#pragma unroll
        for (int rf = 0; rf < 4; rf++) {
#pragma unroll
            for (int i = 0; i < 4; i++) {
                int rowLocal = rf * 16 + r0 + i;
                int row = rowBase + wr * 64 + rowLocal;
                if (row >= N) continue;
                float rm = fmaxf(sMax[wr][0][rowLocal], sMax[wr][1][rowLocal]);
                float rs = rm > 0.f ? 127.f / rm : 0.f;
#pragma unroll
                for (int cf = 0; cf < 4; cf++) {
                    float v = fmaxf(acc[rf][cf][i], 0.f);
                    int col = colBase + wc * 64 + cf * 16 + m;
                    Out[(long)row * NOUT + col] = (bf16_t)v;
                    Hq[(long)row * NOUT + col] =
                        (signed char)fminf(rintf(v * rs), 127.f);
                }
                if (wc == 0 && m == 0)
                    hScale[row * 2 + blockIdx.y] = rm * (1.f / 127.f);
            }
        }
    } else {
#pragma unroll
        for (int rf = 0; rf < 4; rf++) {
#pragma unroll
            for (int i = 0; i < 4; i++) {
                int row = rowBase + wr * 64 + rf * 16 + r0 + i;
                if (row >= N) continue;
#pragma unroll
                for (int cf = 0; cf < 4; cf++) {
                    float v = acc[rf][cf][i];
                    if (RELU) v = fmaxf(v, 0.f);
                    Out[(long)row * NOUT + colBase + wc * 64 + cf * 16 + m] = (bf16_t)v;
                }
            }
        }
    }
}

// ---------- layer-3 GEMM: 96 cols; T3 (cols 0-47) -> int8 stride-64 + scale, R3 -> bf16 stride-48 ----------
__global__ __launch_bounds__(256) void gemm_mfma3(
    const bf16_t* __restrict__ A1, const bf16_t* __restrict__ W1,
    signed char* __restrict__ T3q, float* __restrict__ t3s,
    bf16_t* __restrict__ R3, int N, int K) {
    const int CF = 3, G = 2;
    int lane = threadIdx.x & 63;
    int wid = blockIdx.x * 4 + (threadIdx.x >> 6);
    int rowTile = wid / G;
    int cg = wid - rowTile * G;
    int rowBase = rowTile * 64;
    if (rowBase >= N) return;
    int colBase = cg * 48;
    int m = lane & 15;
    int kq = (lane >> 4) * 8;

    f32x4 acc[4][CF];
#pragma unroll
    for (int a = 0; a < 4; a++)
#pragma unroll
        for (int b = 0; b < CF; b++) acc[a][b] = (f32x4){0.f, 0.f, 0.f, 0.f};

    long ar[4];
#pragma unroll
    for (int rf = 0; rf < 4; rf++) {
        int r = rowBase + rf * 16 + m;
        ar[rf] = (long)min(r, N - 1) * K;
    }

    for (int k0 = kq; k0 < K; k0 += 32) {
        bf16x8 a[4], b[CF];
#pragma unroll
        for (int rf = 0; rf < 4; rf++) a[rf] = *(const bf16x8*)(A1 + ar[rf] + k0);
#pragma unroll
        for (int cf = 0; cf < CF; cf++)
            b[cf] = *(const bf16x8*)(W1 + (long)(colBase + cf * 16 + m) * K + k0);
#pragma unroll
        for (int rf = 0; rf < 4; rf++)
#pragma unroll
            for (int cf = 0; cf < CF; cf++)
                acc[rf][cf] = __builtin_amdgcn_mfma_f32_16x16x32_bf16(a[rf], b[cf], acc[rf][cf], 0, 0, 0);
    }

    int r0 = (lane >> 4) * 4;
#pragma unroll
    for (int rf = 0; rf < 4; rf++) {
#pragma unroll
        for (int i = 0; i < 4; i++) {
            int row = rowBase + rf * 16 + r0 + i;
            if (cg == 0) {
                float mmx = 0.f;
#pragma unroll
                for (int cf = 0; cf < CF; cf++) mmx = fmaxf(mmx, fabsf(acc[rf][cf][i]));
#pragma unroll
                for (int o = 1; o < 16; o <<= 1) mmx = fmaxf(mmx, __shfl_xor(mmx, o));
                if (row < N) {
                    float rs = mmx > 0.f ? 127.f / mmx : 0.f;
#pragma unroll
                    for (int cf = 0; cf < CF; cf++)
                        T3q[(long)row * 64 + cf * 16 + m] =
                            (signed char)fminf(fmaxf(rintf(acc[rf][cf][i] * rs), -127.f), 127.f);
                    if (m == 0) t3s[row] = mmx * (1.f / 127.f);
                }
            } else if (row < N) {
#pragma unroll
                for (int cf = 0; cf < CF; cf++)
                    R3[(long)row * 48 + cf * 16 + m] = (bf16_t)acc[rf][cf][i];
            }
        }
    }
}

// ---------- final: gather int8 T3 (64B rows, 1 line/edge) + dinv + R3 + log_softmax ----------
__global__ void final_fused(const int* __restrict__ rowptr, const int* __restrict__ csr_src,
                            const signed char* __restrict__ T3q, const float* __restrict__ t3s,
                            const bf16_t* __restrict__ R3, const float* __restrict__ dinv,
                            float* __restrict__ out, int N) {
    int wid = blockIdx.x * (blockDim.x >> 6) + (threadIdx.x >> 6);
    int lane = threadIdx.x & 63;
    if (wid >= N) return;
    int s0 = rowptr[wid], s1 = rowptr[wid + 1];
    float a = 0.f, b = 0.f;
    if (lane < 48) {
        int j = s0;
        for (; j + 1 < s1; j += 2) {
            int sa = csr_src[j], sb = csr_src[j + 1];
            a += t3s[sa] * (float)T3q[(long)sa * 64 + lane];
            b += t3s[sb] * (float)T3q[(long)sb * 64 + lane];
        }
        for (; j < s1; j++) {
            int sa = csr_src[j];
            a += t3s[sa] * (float)T3q[(long)sa * 64 + lane];
        }
    }
    bool act = lane < 47;
    float v = act ? (a + b) * dinv[wid] + (float)R3[(long)wid * 48 + lane] : -INFINITY;
    float mx = v;
#pragma unroll
    for (int o = 32; o; o >>= 1) mx = fmaxf(mx, __shfl_xor(mx, o));
    float ex = act ? expf(v - mx) : 0.f;
    float s = ex;
#pragma unroll
    for (int o = 32; o; o >>= 1) s += __shfl_xor(s, o);
    float ls = logf(s);
    if (act) out[(long)wid * 47 + lane] = v - mx - ls;
}

extern "C" void kernel_launch(void* const* d_in, const int* in_sizes, int n_in,
                              void* d_out, int out_size, void* d_ws, size_t ws_size,
                              hipStream_t stream) {
    const float* x   = (const float*)d_in[0];
    const float* Wl1 = (const float*)d_in[1];
    const float* Wr1 = (const float*)d_in[2];
    const float* Wl2 = (const float*)d_in[3];
    const float* Wr2 = (const float*)d_in[4];
    const float* Wl3 = (const float*)d_in[5];
    const float* Wr3 = (const float*)d_in[6];
    const int*   ei  = (const int*)d_in[7];
    float* out = (float*)d_out;
    const int N = NN, E = NE;
    const int NB = (N + 1023) / 1024;  // 49

    char* ws = (char*)d_ws;
    size_t off = 0;
    auto carve = [&](size_t bytes) { void* p = ws + off; off = (off + bytes + 255) & ~(size_t)255; return p; };
    int*    degi     = (int*)carve((size_t)N * 4);
    int*    rowptr   = (int*)carve((size_t)(N + 1) * 4);
    int*    cursor   = (int*)carve((size_t)N * 4);
    int*    csr_src  = (int*)carve((size_t)E * 4);
    int*    partials = (int*)carve(64 * 4);
    float*  dinv     = (float*)carve((size_t)N * 4);
    bf16_t* aggB     = (bf16_t*)carve((size_t)N * 256 * 2);
    bf16_t* xB       = (bf16_t*)carve((size_t)N * 128 * 2);
    signed char* xQ  = (signed char*)carve((size_t)N * 128);
    float*  xScale   = (float*)carve((size_t)N * 4);
    bf16_t* H1       = (bf16_t*)carve((size_t)N * 256 * 2);
    signed char* Hq  = (signed char*)carve((size_t)N * 256);
    float*  hScale   = (float*)carve((size_t)N * 8);   // 2 per row
    bf16_t* H2       = (bf16_t*)carve((size_t)N * 256 * 2);
    bf16_t* wb1l = (bf16_t*)carve(256 * 128 * 2);
    bf16_t* wb1r = (bf16_t*)carve(256 * 128 * 2);
    bf16_t* wb2l = (bf16_t*)carve(256 * 256 * 2);
    bf16_t* wb2r = (bf16_t*)carve(256 * 256 * 2);
    bf16_t* wb3  = (bf16_t*)carve(96 * 256 * 2);
    // layer-3 outputs alias aggB (dead after gemm2 consumes it)
    signed char* T3q = (signed char*)aggB;                                  // N*64 int8
    float*       t3s = (float*)((char*)aggB + (size_t)N * 64);              // N fp32
    bf16_t*      R3  = (bf16_t*)((char*)aggB + (size_t)N * 64 + (size_t)N * 4);  // N*48 bf16

    // --- degi zero + fused converts/deg_count ---
    hipMemsetAsync(degi, 0, (size_t)N * 4, stream);
    cvt_all<<<6250 + 216 + 2344, 256, 0, stream>>>(x, xB, xQ, xScale,
                                                   Wl1, Wr1, Wl2, Wr2, Wl3, Wr3,
                                                   wb1l, wb1r, wb2l, wb2r, wb3, ei, degi);

    // --- CSR build ---
    scan_blocks<<<NB, 1024, 0, stream>>>(degi, rowptr, dinv, partials, N);
    add_offsets<<<(N + 255) / 256, 256, 0, stream>>>(rowptr, cursor, partials, NB, N);
    fill_csr<<<(E + 255) / 256, 256, 0, stream>>>(ei, cursor, csr_src, E);

    const int RT = (N + 127) / 128;  // 391

    // --- layer 1 (int8 gather; GEMM fuses H1 int8 quant) ---
    gather_agg_128<<<(N / 2 + 3) / 4, 256, 0, stream>>>(rowptr, csr_src, xQ, xScale, dinv, aggB, N);
    gemm_lds<128, true, true, true><<<dim3(RT, 2), 256, 0, stream>>>(
        aggB, xB, wb1l, wb1r, H1, N, 256, Hq, hScale);

    // --- layer 2 ---
    gather_agg_256<<<(N / 2 + 3) / 4, 256, 0, stream>>>(rowptr, csr_src, Hq, hScale, dinv, aggB, N);
    gemm_lds<256, true, true, false><<<dim3(RT, 2), 256, 0, stream>>>(
        aggB, H1, wb2l, wb2r, H2, N, 256, nullptr, nullptr);

    // --- layer 3 (T3 int8 fused) + fused gather/log_softmax ---
    gemm_mfma3<<<391, 256, 0, stream>>>(H2, wb3, T3q, t3s, R3, N, 256);
    final_fused<<<(N + 3) / 4, 256, 0, stream>>>(rowptr, csr_src, T3q, t3s, R3, dinv, out, N);
}

// Round 10
// 305.741 us; speedup vs baseline: 1.0623x; 1.0623x over previous
//
#include <hip/hip_runtime.h>
#include <hip/hip_bf16.h>

typedef __bf16 bf16_t;
typedef __bf16 bf16x8 __attribute__((ext_vector_type(8)));
typedef __bf16 bf16x4 __attribute__((ext_vector_type(4)));
typedef float f32x4 __attribute__((ext_vector_type(4)));
typedef signed char i8x4 __attribute__((ext_vector_type(4)));
typedef signed char i8x8 __attribute__((ext_vector_type(8)));

#define NN 50000
#define NE 600000

__device__ __forceinline__ void gload_lds16(const void* g, void* l) {
    __builtin_amdgcn_global_load_lds(
        (const __attribute__((address_space(1))) void*)g,
        (__attribute__((address_space(3))) void*)l, 16, 0, 0);
}

// ---------- fused: x->bf16+int8, weights, deg_count atomics ----------
__global__ void cvt_all(const float* __restrict__ x, bf16_t* __restrict__ xB,
                        signed char* __restrict__ xQ, float* __restrict__ xScale,
                        const float* __restrict__ Wl1, const float* __restrict__ Wr1,
                        const float* __restrict__ Wl2, const float* __restrict__ Wr2,
                        const float* __restrict__ Wl3, const float* __restrict__ Wr3,
                        bf16_t* __restrict__ o1l, bf16_t* __restrict__ o1r,
                        bf16_t* __restrict__ o2l, bf16_t* __restrict__ o2r,
                        bf16_t* __restrict__ o3, const int* __restrict__ ei,
                        int* __restrict__ degi) {
    int b = blockIdx.x;
    if (b < 6250) {
        int hw = threadIdx.x >> 5, sub = threadIdx.x & 31;
        int row = b * 8 + hw;  // 6250*8 == 50000 exactly
        float4 v = *(const float4*)(x + (long)row * 128 + sub * 4);
        bf16x4 o;
        o[0] = (bf16_t)v.x; o[1] = (bf16_t)v.y; o[2] = (bf16_t)v.z; o[3] = (bf16_t)v.w;
        *(bf16x4*)(xB + (long)row * 128 + sub * 4) = o;
        float m = fmaxf(fmaxf(fabsf(v.x), fabsf(v.y)), fmaxf(fabsf(v.z), fabsf(v.w)));
#pragma unroll
        for (int o2 = 1; o2 < 32; o2 <<= 1) m = fmaxf(m, __shfl_xor(m, o2));
        float rs = m > 0.f ? 127.f / m : 0.f;
        i8x4 q;
        q[0] = (signed char)fminf(fmaxf(rintf(v.x * rs), -127.f), 127.f);
        q[1] = (signed char)fminf(fmaxf(rintf(v.y * rs), -127.f), 127.f);
        q[2] = (signed char)fminf(fmaxf(rintf(v.z * rs), -127.f), 127.f);
        q[3] = (signed char)fminf(fmaxf(rintf(v.w * rs), -127.f), 127.f);
        *(i8x4*)(xQ + (long)row * 128 + sub * 4) = q;
        if (sub == 0) xScale[row] = m * (1.f / 127.f);
    } else if (b < 6466) {
        int t = (b - 6250) * 256 + threadIdx.x;  // [0, 55296)
        bf16x4 o;
        if (t < 49152) {
            const float* in; bf16_t* out; int g;
            if (t < 8192)       { in = Wl1; out = o1l; g = t; }
            else if (t < 16384) { in = Wr1; out = o1r; g = t - 8192; }
            else if (t < 32768) { in = Wl2; out = o2l; g = t - 16384; }
            else                { in = Wr2; out = o2r; g = t - 32768; }
            float4 v = ((const float4*)in)[g];
            o[0] = (bf16_t)v.x; o[1] = (bf16_t)v.y; o[2] = (bf16_t)v.z; o[3] = (bf16_t)v.w;
            ((bf16x4*)out)[g] = o;
        } else if (t < 55296) {
            int g = t - 49152;
            int row = g >> 6, c4 = (g & 63) * 4;  // row in [0,96)
            const float* src = nullptr;
            int srow = 0;
            if (row < 47) { src = Wl3; srow = row; }
            else if (row >= 48 && row < 95) { src = Wr3; srow = row - 48; }
            if (src) {
                float4 v = *(const float4*)(src + srow * 256 + c4);
                o[0] = (bf16_t)v.x; o[1] = (bf16_t)v.y; o[2] = (bf16_t)v.z; o[3] = (bf16_t)v.w;
            } else {
                o[0] = o[1] = o[2] = o[3] = (bf16_t)0.f;
            }
            *(bf16x4*)(o3 + row * 256 + c4) = o;
        }
    } else {
        int e = (b - 6466) * 256 + threadIdx.x;
        if (e < NE) atomicAdd(&degi[ei[NE + e]], 1);
    }
}

// ---------- CSR build ----------
__global__ __launch_bounds__(1024) void scan_blocks(const int* __restrict__ degi,
                                                    int* __restrict__ rowptr,
                                                    float* __restrict__ dinv,
                                                    int* __restrict__ partials, int n) {
    int i = blockIdx.x * 1024 + threadIdx.x;
    int v = (i < n) ? degi[i] : 0;
    int lane = threadIdx.x & 63;
    int w = threadIdx.x >> 6;
    int s = v;
#pragma unroll
    for (int o = 1; o < 64; o <<= 1) {
        int t = __shfl_up(s, o);
        if (lane >= o) s += t;
    }
    __shared__ int wsum[16];
    if (lane == 63) wsum[w] = s;
    __syncthreads();
    if (threadIdx.x < 16) {
        int t = wsum[threadIdx.x];
#pragma unroll
        for (int o = 1; o < 16; o <<= 1) {
            int u = __shfl_up(t, o);
            if ((int)threadIdx.x >= o) t += u;
        }
        wsum[threadIdx.x] = t;
    }
    __syncthreads();
    int incl = s + ((w > 0) ? wsum[w - 1] : 0);
    if (i < n) {
        rowptr[i] = incl - v;
        dinv[i] = 1.0f / fmaxf((float)v, 1.0f);
    }
    if (threadIdx.x == 1023) partials[blockIdx.x] = incl;
}

__global__ void add_offsets(int* __restrict__ rowptr, int* __restrict__ cursor,
                            const int* __restrict__ partials, int nb, int n) {
    __shared__ int bofs[64];
    __shared__ int total_s;
    if (threadIdx.x < 64) {
        int lane = threadIdx.x;
        int v = (lane < nb) ? partials[lane] : 0;
        int s = v;
#pragma unroll
        for (int o = 1; o < 64; o <<= 1) {
            int t = __shfl_up(s, o);
            if (lane >= o) s += t;
        }
        bofs[lane] = s - v;
        if (lane == nb - 1) total_s = s;
    }
    __syncthreads();
    int i = blockIdx.x * blockDim.x + threadIdx.x;
    if (i < n) {
        int v = rowptr[i] + bofs[i >> 10];
        rowptr[i] = v;
        cursor[i] = v;
    }
    if (blockIdx.x == 0 && threadIdx.x == 0) rowptr[n] = total_s;
}

__global__ void fill_csr(const int* __restrict__ ei, int* __restrict__ cursor,
                         int* __restrict__ csr_src, int E) {
    int e = blockIdx.x * blockDim.x + threadIdx.x;
    if (e >= E) return;
    int d = ei[E + e];
    int pos = atomicAdd(&cursor[d], 1);
    csr_src[pos] = ei[e];
}

// ---------- gather aggregations: half-wave per node, batched edge indices ----------
// Batch phase: 32 lanes cooperatively load up to 32 edge indices + scales (coalesced).
// Inner loop: shfl-broadcast (no memory dep), independent row loads 2-deep.
__global__ void gather_agg_128(const int* __restrict__ rowptr, const int* __restrict__ csr_src,
                               const signed char* __restrict__ Xq, const float* __restrict__ xScale,
                               const float* __restrict__ dinv, bf16_t* __restrict__ out, int N) {
    int wv = blockIdx.x * (blockDim.x >> 6) + (threadIdx.x >> 6);
    int lane = threadIdx.x & 63;
    int node = wv * 2 + (lane >> 5);
    if (node >= N) return;
    int sub = lane & 31;
    int hb = lane & 32;  // shfl base for this half-wave
    int c = sub * 4;
    int s0 = rowptr[node], s1 = rowptr[node + 1];
    float acc[4] = {0.f, 0.f, 0.f, 0.f};
    for (int base = s0; base < s1; base += 32) {
        int cnt = min(32, s1 - base);
        int idx = 0; float sc = 0.f;
        if (sub < cnt) { idx = csr_src[base + sub]; sc = xScale[idx]; }
        int k = 0;
        for (; k + 2 <= cnt; k += 2) {
            int i0 = __shfl(idx, hb + k), i1 = __shfl(idx, hb + k + 1);
            float c0 = __shfl(sc, hb + k), c1 = __shfl(sc, hb + k + 1);
            i8x4 v0 = *(const i8x4*)(Xq + (long)i0 * 128 + c);
            i8x4 v1 = *(const i8x4*)(Xq + (long)i1 * 128 + c);
#pragma unroll
            for (int i = 0; i < 4; i++) acc[i] += c0 * (float)v0[i] + c1 * (float)v1[i];
        }
        if (k < cnt) {
            int i0 = __shfl(idx, hb + k);
            float c0 = __shfl(sc, hb + k);
            i8x4 v0 = *(const i8x4*)(Xq + (long)i0 * 128 + c);
#pragma unroll
            for (int i = 0; i < 4; i++) acc[i] += c0 * (float)v0[i];
        }
    }
    float di = dinv[node];
    bf16x4 o;
#pragma unroll
    for (int i = 0; i < 4; i++) o[i] = (bf16_t)(acc[i] * di);
    *(bf16x4*)(out + (long)node * 128 + c) = o;
}

// C=256 int8 rows; per-(row,half) scales loaded as float2 in the batch phase.
__global__ void gather_agg_256(const int* __restrict__ rowptr, const int* __restrict__ csr_src,
                               const signed char* __restrict__ Hq, const float* __restrict__ hScale,
                               const float* __restrict__ dinv, bf16_t* __restrict__ out, int N) {
    int wv = blockIdx.x * (blockDim.x >> 6) + (threadIdx.x >> 6);
    int lane = threadIdx.x & 63;
    int node = wv * 2 + (lane >> 5);
    if (node >= N) return;
    int sub = lane & 31;
    int hb = lane & 32;
    int c = sub * 8;
    int half = sub >> 4;
    int s0 = rowptr[node], s1 = rowptr[node + 1];
    float acc[8] = {0.f, 0.f, 0.f, 0.f, 0.f, 0.f, 0.f, 0.f};
    for (int base = s0; base < s1; base += 32) {
        int cnt = min(32, s1 - base);
        int idx = 0; float sA = 0.f, sB = 0.f;
        if (sub < cnt) {
            idx = csr_src[base + sub];
            float2 sp = *(const float2*)(hScale + idx * 2);
            sA = sp.x; sB = sp.y;
        }
        int k = 0;
        for (; k + 2 <= cnt; k += 2) {
            int i0 = __shfl(idx, hb + k), i1 = __shfl(idx, hb + k + 1);
            float a0 = __shfl(sA, hb + k), a1 = __shfl(sA, hb + k + 1);
            float b0 = __shfl(sB, hb + k), b1 = __shfl(sB, hb + k + 1);
            float c0 = half ? b0 : a0, c1 = half ? b1 : a1;
            i8x8 v0 = *(const i8x8*)(Hq + (long)i0 * 256 + c);
            i8x8 v1 = *(const i8x8*)(Hq + (long)i1 * 256 + c);
#pragma unroll
            for (int i = 0; i < 8; i++) acc[i] += c0 * (float)v0[i] + c1 * (float)v1[i];
        }
        if (k < cnt) {
            int i0 = __shfl(idx, hb + k);
            float a0 = __shfl(sA, hb + k), b0 = __shfl(sB, hb + k);
            float c0 = half ? b0 : a0;
            i8x8 v0 = *(const i8x8*)(Hq + (long)i0 * 256 + c);
#pragma unroll
            for (int i = 0; i < 8; i++) acc[i] += c0 * (float)v0[i];
        }
    }
    float di = dinv[node];
    bf16x8 o;
#pragma unroll
    for (int i = 0; i < 8; i++) o[i] = (bf16_t)(acc[i] * di);
    *(bf16x8*)(out + (long)node * 256 + c) = o;
}

// ---------- LDS-staged MFMA GEMM: 128x128 tile, BK=64; optional fused int8 quant ----------
template <int KTOT, bool DUAL, bool RELU, bool QUANT>
__global__ __launch_bounds__(256) void gemm_lds(
    const bf16_t* __restrict__ A1, const bf16_t* __restrict__ A2,
    const bf16_t* __restrict__ W1, const bf16_t* __restrict__ W2,
    bf16_t* __restrict__ Out, int N, int NOUT,
    signed char* __restrict__ Hq, float* __restrict__ hScale) {
    __shared__ bf16_t As[128 * 64];
    __shared__ bf16_t Bs[128 * 64];
    __shared__ float sMax[2][2][64];
    int tid = threadIdx.x;
    int w = tid >> 6, lane = tid & 63;
    int wr = w >> 1, wc = w & 1;
    int rowBase = blockIdx.x * 128;
    int colBase = blockIdx.y * 128;
    int m = lane & 15, q = lane >> 4;

    long aoff[4], boff[4];
    int ldsOff[4];
#pragma unroll
    for (int i = 0; i < 4; i++) {
        int c = w * 256 + i * 64 + lane;
        int r = c >> 3, s = c & 7;
        int gk = (s ^ (r & 7)) << 3;
        aoff[i] = (long)min(rowBase + r, N - 1) * KTOT + gk;
        boff[i] = (long)(colBase + r) * KTOT + gk;
        ldsOff[i] = (w * 4 + i) * 512;
    }

    f32x4 acc[4][4];
#pragma unroll
    for (int a = 0; a < 4; a++)
#pragma unroll
        for (int b = 0; b < 4; b++) acc[a][b] = (f32x4){0.f, 0.f, 0.f, 0.f};

#pragma unroll
    for (int half = 0; half < (DUAL ? 2 : 1); half++) {
        const bf16_t* A = half ? A2 : A1;
        const bf16_t* W = half ? W2 : W1;
#pragma unroll
        for (int k0 = 0; k0 < KTOT; k0 += 64) {
            __syncthreads();
#pragma unroll
            for (int i = 0; i < 4; i++) {
                gload_lds16(A + aoff[i] + k0, As + ldsOff[i]);
                gload_lds16(W + boff[i] + k0, Bs + ldsOff[i]);
            }
            __syncthreads();
#pragma unroll
            for (int ks = 0; ks < 2; ks++) {
                bf16x8 af[4], bfr[4];
#pragma unroll
                for (int rf = 0; rf < 4; rf++) {
                    int r = wr * 64 + rf * 16 + m;
                    int seg = ks * 4 + q;
                    af[rf] = *(const bf16x8*)(As + r * 64 + ((seg ^ (r & 7)) << 3));
                }
#pragma unroll
                for (int cf = 0; cf < 4; cf++) {
                    int r = wc * 64 + cf * 16 + m;
                    int seg = ks * 4 + q;
                    bfr[cf] = *(const bf16x8*)(Bs + r * 64 + ((seg ^ (r & 7)) << 3));
                }
#pragma unroll
                for (int rf = 0; rf < 4; rf++)
#pragma unroll
                    for (int cf = 0; cf < 4; cf++)
                        acc[rf][cf] = __builtin_amdgcn_mfma_f32_16x16x32_bf16(af[rf], bfr[cf], acc[rf][cf], 0, 0, 0);
            }
        }
    }

    int r0 = q * 4;
    if constexpr (QUANT) {
        float mm[4][4];
#pragma unroll
        for (int rf = 0; rf < 4; rf++)
#pragma unroll
            for (int i = 0; i < 4; i++) {
                float t = 0.f;
#pragma unroll
                for (int cf = 0; cf < 4; cf++) t = fmaxf(t, fmaxf(acc[rf][cf][i], 0.f));
                mm[rf][i] = t;
            }
#pragma unroll
        for (int o = 1; o < 16; o <<= 1)
#pragma unroll
            for (int rf = 0; rf < 4; rf++)
#pragma unroll
                for (int i = 0; i < 4; i++) mm[rf][i] = fmaxf(mm[rf][i], __shfl_xor(mm[rf][i], o));
        __syncthreads();
        if (m == 0) {
#pragma unroll
            for (int rf = 0; rf < 4; rf++)
#pragma unroll
                for (int i = 0; i < 4; i++) sMax[wr][wc][rf * 16 + q * 4 + i] = mm[rf][i];
        }
        __syncthreads();
#pragma unroll
        for (int rf = 0; rf < 4; rf++) {
#pragma unroll
            for (int i = 0; i < 4; i++) {
                int rowLocal = rf * 16 + r0 + i;
                int row = rowBase + wr * 64 + rowLocal;
                if (row >= N) continue;
                float rm = fmaxf(sMax[wr][0][rowLocal], sMax[wr][1][rowLocal]);
                float rs = rm > 0.f ? 127.f / rm : 0.f;
#pragma unroll
                for (int cf = 0; cf < 4; cf++) {
                    float v = fmaxf(acc[rf][cf][i], 0.f);
                    int col = colBase + wc * 64 + cf * 16 + m;
                    Out[(long)row * NOUT + col] = (bf16_t)v;
                    Hq[(long)row * NOUT + col] =
                        (signed char)fminf(rintf(v * rs), 127.f);
                }
                if (wc == 0 && m == 0)
                    hScale[row * 2 + blockIdx.y] = rm * (1.f / 127.f);
            }
        }
    } else {
#pragma unroll
        for (int rf = 0; rf < 4; rf++) {
#pragma unroll
            for (int i = 0; i < 4; i++) {
                int row = rowBase + wr * 64 + rf * 16 + r0 + i;
                if (row >= N) continue;
#pragma unroll
                for (int cf = 0; cf < 4; cf++) {
                    float v = acc[rf][cf][i];
                    if (RELU) v = fmaxf(v, 0.f);
                    Out[(long)row * NOUT + colBase + wc * 64 + cf * 16 + m] = (bf16_t)v;
                }
            }
        }
    }
}

// ---------- layer-3 GEMM: 96 cols; T3 -> int8 stride-64 + scale, R3 -> bf16 stride-48 ----------
__global__ __launch_bounds__(256) void gemm_mfma3(
    const bf16_t* __restrict__ A1, const bf16_t* __restrict__ W1,
    signed char* __restrict__ T3q, float* __restrict__ t3s,
    bf16_t* __restrict__ R3, int N, int K) {
    const int CF = 3, G = 2;
    int lane = threadIdx.x & 63;
    int wid = blockIdx.x * 4 + (threadIdx.x >> 6);
    int rowTile = wid / G;
    int cg = wid - rowTile * G;
    int rowBase = rowTile * 64;
    if (rowBase >= N) return;
    int colBase = cg * 48;
    int m = lane & 15;
    int kq = (lane >> 4) * 8;

    f32x4 acc[4][CF];
#pragma unroll
    for (int a = 0; a < 4; a++)
#pragma unroll
        for (int b = 0; b < CF; b++) acc[a][b] = (f32x4){0.f, 0.f, 0.f, 0.f};

    long ar[4];
#pragma unroll
    for (int rf = 0; rf < 4; rf++) {
        int r = rowBase + rf * 16 + m;
        ar[rf] = (long)min(r, N - 1) * K;
    }

    for (int k0 = kq; k0 < K; k0 += 32) {
        bf16x8 a[4], b[CF];
#pragma unroll
        for (int rf = 0; rf < 4; rf++) a[rf] = *(const bf16x8*)(A1 + ar[rf] + k0);
#pragma unroll
        for (int cf = 0; cf < CF; cf++)
            b[cf] = *(const bf16x8*)(W1 + (long)(colBase + cf * 16 + m) * K + k0);
#pragma unroll
        for (int rf = 0; rf < 4; rf++)
#pragma unroll
            for (int cf = 0; cf < CF; cf++)
                acc[rf][cf] = __builtin_amdgcn_mfma_f32_16x16x32_bf16(a[rf], b[cf], acc[rf][cf], 0, 0, 0);
    }

    int r0 = (lane >> 4) * 4;
#pragma unroll
    for (int rf = 0; rf < 4; rf++) {
#pragma unroll
        for (int i = 0; i < 4; i++) {
            int row = rowBase + rf * 16 + r0 + i;
            if (cg == 0) {
                float mmx = 0.f;
#pragma unroll
                for (int cf = 0; cf < CF; cf++) mmx = fmaxf(mmx, fabsf(acc[rf][cf][i]));
#pragma unroll
                for (int o = 1; o < 16; o <<= 1) mmx = fmaxf(mmx, __shfl_xor(mmx, o));
                if (row < N) {
                    float rs = mmx > 0.f ? 127.f / mmx : 0.f;
#pragma unroll
                    for (int cf = 0; cf < CF; cf++)
                        T3q[(long)row * 64 + cf * 16 + m] =
                            (signed char)fminf(fmaxf(rintf(acc[rf][cf][i] * rs), -127.f), 127.f);
                    if (m == 0) t3s[row] = mmx * (1.f / 127.f);
                }
            } else if (row < N) {
#pragma unroll
                for (int cf = 0; cf < CF; cf++)
                    R3[(long)row * 48 + cf * 16 + m] = (bf16_t)acc[rf][cf][i];
            }
        }
    }
}

// ---------- final: batched-edge gather of int8 T3 + dinv + R3 + log_softmax ----------
__global__ void final_fused(const int* __restrict__ rowptr, const int* __restrict__ csr_src,
                            const signed char* __restrict__ T3q, const float* __restrict__ t3s,
                            const bf16_t* __restrict__ R3, const float* __restrict__ dinv,
                            float* __restrict__ out, int N) {
    int wid = blockIdx.x * (blockDim.x >> 6) + (threadIdx.x >> 6);
    int lane = threadIdx.x & 63;
    if (wid >= N) return;
    int s0 = rowptr[wid], s1 = rowptr[wid + 1];
    float acc = 0.f;
    // all 64 lanes load (row stride 64B => in-bounds); lanes >=47 masked at softmax
    for (int base = s0; base < s1; base += 64) {
        int cnt = min(64, s1 - base);
        int idx = 0; float sc = 0.f;
        if (lane < cnt) { idx = csr_src[base + lane]; sc = t3s[idx]; }
        int k = 0;
        for (; k + 4 <= cnt; k += 4) {
            int i0 = __shfl(idx, k), i1 = __shfl(idx, k + 1);
            int i2 = __shfl(idx, k + 2), i3 = __shfl(idx, k + 3);
            float c0 = __shfl(sc, k), c1 = __shfl(sc, k + 1);
            float c2 = __shfl(sc, k + 2), c3 = __shfl(sc, k + 3);
            float v0 = (float)T3q[(long)i0 * 64 + lane];
            float v1 = (float)T3q[(long)i1 * 64 + lane];
            float v2 = (float)T3q[(long)i2 * 64 + lane];
            float v3 = (float)T3q[(long)i3 * 64 + lane];
            acc += c0 * v0 + c1 * v1 + c2 * v2 + c3 * v3;
        }
        for (; k < cnt; k++) {
            int i0 = __shfl(idx, k);
            float c0 = __shfl(sc, k);
            acc += c0 * (float)T3q[(long)i0 * 64 + lane];
        }
    }
    bool act = lane < 47;
    float v = act ? acc * dinv[wid] + (float)R3[(long)wid * 48 + lane] : -INFINITY;
    float mx = v;
#pragma unroll
    for (int o = 32; o; o >>= 1) mx = fmaxf(mx, __shfl_xor(mx, o));
    float ex = act ? expf(v - mx) : 0.f;
    float s = ex;
#pragma unroll
    for (int o = 32; o; o >>= 1) s += __shfl_xor(s, o);
    float ls = logf(s);
    if (act) out[(long)wid * 47 + lane] = v - mx - ls;
}

extern "C" void kernel_launch(void* const* d_in, const int* in_sizes, int n_in,
                              void* d_out, int out_size, void* d_ws, size_t ws_size,
                              hipStream_t stream) {
    const float* x   = (const float*)d_in[0];
    const float* Wl1 = (const float*)d_in[1];
    const float* Wr1 = (const float*)d_in[2];
    const float* Wl2 = (const float*)d_in[3];
    const float* Wr2 = (const float*)d_in[4];
    const float* Wl3 = (const float*)d_in[5];
    const float* Wr3 = (const float*)d_in[6];
    const int*   ei  = (const int*)d_in[7];
    float* out = (float*)d_out;
    const int N = NN, E = NE;
    const int NB = (N + 1023) / 1024;  // 49

    char* ws = (char*)d_ws;
    size_t off = 0;
    auto carve = [&](size_t bytes) { void* p = ws + off; off = (off + bytes + 255) & ~(size_t)255; return p; };
    int*    degi     = (int*)carve((size_t)N * 4);
    int*    rowptr   = (int*)carve((size_t)(N + 1) * 4);
    int*    cursor   = (int*)carve((size_t)N * 4);
    int*    csr_src  = (int*)carve((size_t)E * 4);
    int*    partials = (int*)carve(64 * 4);
    float*  dinv     = (float*)carve((size_t)N * 4);
    bf16_t* aggB     = (bf16_t*)carve((size_t)N * 256 * 2);
    bf16_t* xB       = (bf16_t*)carve((size_t)N * 128 * 2);
    signed char* xQ  = (signed char*)carve((size_t)N * 128);
    float*  xScale   = (float*)carve((size_t)N * 4);
    bf16_t* H1       = (bf16_t*)carve((size_t)N * 256 * 2);
    signed char* Hq  = (signed char*)carve((size_t)N * 256);
    float*  hScale   = (float*)carve((size_t)N * 8);   // 2 per row
    bf16_t* H2       = (bf16_t*)carve((size_t)N * 256 * 2);
    bf16_t* wb1l = (bf16_t*)carve(256 * 128 * 2);
    bf16_t* wb1r = (bf16_t*)carve(256 * 128 * 2);
    bf16_t* wb2l = (bf16_t*)carve(256 * 256 * 2);
    bf16_t* wb2r = (bf16_t*)carve(256 * 256 * 2);
    bf16_t* wb3  = (bf16_t*)carve(96 * 256 * 2);
    signed char* T3q = (signed char*)aggB;                                  // N*64 int8
    float*       t3s = (float*)((char*)aggB + (size_t)N * 64);              // N fp32
    bf16_t*      R3  = (bf16_t*)((char*)aggB + (size_t)N * 64 + (size_t)N * 4);  // N*48 bf16

    // --- degi zero + fused converts/deg_count ---
    hipMemsetAsync(degi, 0, (size_t)N * 4, stream);
    cvt_all<<<6250 + 216 + 2344, 256, 0, stream>>>(x, xB, xQ, xScale,
                                                   Wl1, Wr1, Wl2, Wr2, Wl3, Wr3,
                                                   wb1l, wb1r, wb2l, wb2r, wb3, ei, degi);

    // --- CSR build ---
    scan_blocks<<<NB, 1024, 0, stream>>>(degi, rowptr, dinv, partials, N);
    add_offsets<<<(N + 255) / 256, 256, 0, stream>>>(rowptr, cursor, partials, NB, N);
    fill_csr<<<(E + 255) / 256, 256, 0, stream>>>(ei, cursor, csr_src, E);

    const int RT = (N + 127) / 128;  // 391

    // --- layer 1 (int8 gather; GEMM fuses H1 int8 quant) ---
    gather_agg_128<<<(N / 2 + 3) / 4, 256, 0, stream>>>(rowptr, csr_src, xQ, xScale, dinv, aggB, N);
    gemm_lds<128, true, true, true><<<dim3(RT, 2), 256, 0, stream>>>(
        aggB, xB, wb1l, wb1r, H1, N, 256, Hq, hScale);

    // --- layer 2 ---
    gather_agg_256<<<(N / 2 + 3) / 4, 256, 0, stream>>>(rowptr, csr_src, Hq, hScale, dinv, aggB, N);
    gemm_lds<256, true, true, false><<<dim3(RT, 2), 256, 0, stream>>>(
        aggB, H1, wb2l, wb2r, H2, N, 256, nullptr, nullptr);

    // --- layer 3 (T3 int8 fused) + fused gather/log_softmax ---
    gemm_mfma3<<<391, 256, 0, stream>>>(H2, wb3, T3q, t3s, R3, N, 256);
    final_fused<<<(N + 3) / 4, 256, 0, stream>>>(rowptr, csr_src, T3q, t3s, R3, dinv, out, N);
}

// Round 11
// 284.643 us; speedup vs baseline: 1.1410x; 1.0741x over previous
//
#include <hip/hip_runtime.h>
#include <hip/hip_bf16.h>

typedef __bf16 bf16_t;
typedef __bf16 bf16x8 __attribute__((ext_vector_type(8)));
typedef __bf16 bf16x4 __attribute__((ext_vector_type(4)));
typedef float f32x4 __attribute__((ext_vector_type(4)));
typedef signed char i8x4 __attribute__((ext_vector_type(4)));
typedef signed char i8x8 __attribute__((ext_vector_type(8)));

#define NN 50000
#define NE 600000

__device__ __forceinline__ void gload_lds16(const void* g, void* l) {
    __builtin_amdgcn_global_load_lds(
        (const __attribute__((address_space(1))) void*)g,
        (__attribute__((address_space(3))) void*)l, 16, 0, 0);
}

// ---------- fused: x->bf16+int8, weights, deg_count atomics (+rank capture) ----------
__global__ void cvt_all(const float* __restrict__ x, bf16_t* __restrict__ xB,
                        signed char* __restrict__ xQ, float* __restrict__ xScale,
                        const float* __restrict__ Wl1, const float* __restrict__ Wr1,
                        const float* __restrict__ Wl2, const float* __restrict__ Wr2,
                        const float* __restrict__ Wl3, const float* __restrict__ Wr3,
                        bf16_t* __restrict__ o1l, bf16_t* __restrict__ o1r,
                        bf16_t* __restrict__ o2l, bf16_t* __restrict__ o2r,
                        bf16_t* __restrict__ o3, const int* __restrict__ ei,
                        int* __restrict__ degi, int* __restrict__ rank) {
    int b = blockIdx.x;
    if (b < 6250) {
        int hw = threadIdx.x >> 5, sub = threadIdx.x & 31;
        int row = b * 8 + hw;  // 6250*8 == 50000 exactly
        float4 v = *(const float4*)(x + (long)row * 128 + sub * 4);
        bf16x4 o;
        o[0] = (bf16_t)v.x; o[1] = (bf16_t)v.y; o[2] = (bf16_t)v.z; o[3] = (bf16_t)v.w;
        *(bf16x4*)(xB + (long)row * 128 + sub * 4) = o;
        float m = fmaxf(fmaxf(fabsf(v.x), fabsf(v.y)), fmaxf(fabsf(v.z), fabsf(v.w)));
#pragma unroll
        for (int o2 = 1; o2 < 32; o2 <<= 1) m = fmaxf(m, __shfl_xor(m, o2));
        float rs = m > 0.f ? 127.f / m : 0.f;
        i8x4 q;
        q[0] = (signed char)fminf(fmaxf(rintf(v.x * rs), -127.f), 127.f);
        q[1] = (signed char)fminf(fmaxf(rintf(v.y * rs), -127.f), 127.f);
        q[2] = (signed char)fminf(fmaxf(rintf(v.z * rs), -127.f), 127.f);
        q[3] = (signed char)fminf(fmaxf(rintf(v.w * rs), -127.f), 127.f);
        *(i8x4*)(xQ + (long)row * 128 + sub * 4) = q;
        if (sub == 0) xScale[row] = m * (1.f / 127.f);
    } else if (b < 6466) {
        int t = (b - 6250) * 256 + threadIdx.x;  // [0, 55296)
        bf16x4 o;
        if (t < 49152) {
            const float* in; bf16_t* out; int g;
            if (t < 8192)       { in = Wl1; out = o1l; g = t; }
            else if (t < 16384) { in = Wr1; out = o1r; g = t - 8192; }
            else if (t < 32768) { in = Wl2; out = o2l; g = t - 16384; }
            else                { in = Wr2; out = o2r; g = t - 32768; }
            float4 v = ((const float4*)in)[g];
            o[0] = (bf16_t)v.x; o[1] = (bf16_t)v.y; o[2] = (bf16_t)v.z; o[3] = (bf16_t)v.w;
            ((bf16x4*)out)[g] = o;
        } else if (t < 55296) {
            int g = t - 49152;
            int row = g >> 6, c4 = (g & 63) * 4;  // row in [0,96)
            const float* src = nullptr;
            int srow = 0;
            if (row < 47) { src = Wl3; srow = row; }
            else if (row >= 48 && row < 95) { src = Wr3; srow = row - 48; }
            if (src) {
                float4 v = *(const float4*)(src + srow * 256 + c4);
                o[0] = (bf16_t)v.x; o[1] = (bf16_t)v.y; o[2] = (bf16_t)v.z; o[3] = (bf16_t)v.w;
            } else {
                o[0] = o[1] = o[2] = o[3] = (bf16_t)0.f;
            }
            *(bf16x4*)(o3 + row * 256 + c4) = o;
        }
    } else {
        int e = (b - 6466) * 256 + threadIdx.x;
        if (e < NE) rank[e] = atomicAdd(&degi[ei[NE + e]], 1);
    }
}

// ---------- CSR build ----------
__global__ __launch_bounds__(1024) void scan_blocks(const int* __restrict__ degi,
                                                    int* __restrict__ rowptr,
                                                    float* __restrict__ dinv,
                                                    int* __restrict__ partials, int n) {
    int i = blockIdx.x * 1024 + threadIdx.x;
    int v = (i < n) ? degi[i] : 0;
    int lane = threadIdx.x & 63;
    int w = threadIdx.x >> 6;
    int s = v;
#pragma unroll
    for (int o = 1; o < 64; o <<= 1) {
        int t = __shfl_up(s, o);
        if (lane >= o) s += t;
    }
    __shared__ int wsum[16];
    if (lane == 63) wsum[w] = s;
    __syncthreads();
    if (threadIdx.x < 16) {
        int t = wsum[threadIdx.x];
#pragma unroll
        for (int o = 1; o < 16; o <<= 1) {
            int u = __shfl_up(t, o);
            if ((int)threadIdx.x >= o) t += u;
        }
        wsum[threadIdx.x] = t;
    }
    __syncthreads();
    int incl = s + ((w > 0) ? wsum[w - 1] : 0);
    if (i < n) {
        rowptr[i] = incl - v;
        dinv[i] = 1.0f / fmaxf((float)v, 1.0f);
    }
    if (threadIdx.x == 1023) partials[blockIdx.x] = incl;
}

__global__ void add_offsets(int* __restrict__ rowptr, const int* __restrict__ partials,
                            int nb, int n) {
    __shared__ int bofs[64];
    __shared__ int total_s;
    if (threadIdx.x < 64) {
        int lane = threadIdx.x;
        int v = (lane < nb) ? partials[lane] : 0;
        int s = v;
#pragma unroll
        for (int o = 1; o < 64; o <<= 1) {
            int t = __shfl_up(s, o);
            if (lane >= o) s += t;
        }
        bofs[lane] = s - v;
        if (lane == nb - 1) total_s = s;
    }
    __syncthreads();
    int i = blockIdx.x * blockDim.x + threadIdx.x;
    if (i < n) rowptr[i] += bofs[i >> 10];
    if (blockIdx.x == 0 && threadIdx.x == 0) rowptr[n] = total_s;
}

// atomic-free: pos = rowptr[dst] + precomputed rank. 2 edges/thread for ILP.
__global__ void fill_csr(const int* __restrict__ ei, const int* __restrict__ rank,
                         const int* __restrict__ rowptr, int* __restrict__ csr_src, int E) {
    int e = (blockIdx.x * blockDim.x + threadIdx.x) * 2;
    if (e + 1 < E) {
        int2 d = *(const int2*)(ei + E + e);
        int2 r = *(const int2*)(rank + e);
        int2 s = *(const int2*)(ei + e);
        int p0 = rowptr[d.x] + r.x;
        int p1 = rowptr[d.y] + r.y;
        csr_src[p0] = s.x;
        csr_src[p1] = s.y;
    } else if (e < E) {
        csr_src[rowptr[ei[E + e]] + rank[e]] = ei[e];
    }
}

// ---------- gather aggregations: half-wave per node, batched edge indices ----------
__global__ void gather_agg_128(const int* __restrict__ rowptr, const int* __restrict__ csr_src,
                               const signed char* __restrict__ Xq, const float* __restrict__ xScale,
                               const float* __restrict__ dinv, bf16_t* __restrict__ out, int N) {
    int wv = blockIdx.x * (blockDim.x >> 6) + (threadIdx.x >> 6);
    int lane = threadIdx.x & 63;
    int node = wv * 2 + (lane >> 5);
    if (node >= N) return;
    int sub = lane & 31;
    int hb = lane & 32;  // shfl base for this half-wave
    int c = sub * 4;
    int s0 = rowptr[node], s1 = rowptr[node + 1];
    float acc[4] = {0.f, 0.f, 0.f, 0.f};
    for (int base = s0; base < s1; base += 32) {
        int cnt = min(32, s1 - base);
        int idx = 0; float sc = 0.f;
        if (sub < cnt) { idx = csr_src[base + sub]; sc = xScale[idx]; }
        int k = 0;
        for (; k + 2 <= cnt; k += 2) {
            int i0 = __shfl(idx, hb + k), i1 = __shfl(idx, hb + k + 1);
            float c0 = __shfl(sc, hb + k), c1 = __shfl(sc, hb + k + 1);
            i8x4 v0 = *(const i8x4*)(Xq + (long)i0 * 128 + c);
            i8x4 v1 = *(const i8x4*)(Xq + (long)i1 * 128 + c);
#pragma unroll
            for (int i = 0; i < 4; i++) acc[i] += c0 * (float)v0[i] + c1 * (float)v1[i];
        }
        if (k < cnt) {
            int i0 = __shfl(idx, hb + k);
            float c0 = __shfl(sc, hb + k);
            i8x4 v0 = *(const i8x4*)(Xq + (long)i0 * 128 + c);
#pragma unroll
            for (int i = 0; i < 4; i++) acc[i] += c0 * (float)v0[i];
        }
    }
    float di = dinv[node];
    bf16x4 o;
#pragma unroll
    for (int i = 0; i < 4; i++) o[i] = (bf16_t)(acc[i] * di);
    *(bf16x4*)(out + (long)node * 128 + c) = o;
}

__global__ void gather_agg_256(const int* __restrict__ rowptr, const int* __restrict__ csr_src,
                               const signed char* __restrict__ Hq, const float* __restrict__ hScale,
                               const float* __restrict__ dinv, bf16_t* __restrict__ out, int N) {
    int wv = blockIdx.x * (blockDim.x >> 6) + (threadIdx.x >> 6);
    int lane = threadIdx.x & 63;
    int node = wv * 2 + (lane >> 5);
    if (node >= N) return;
    int sub = lane & 31;
    int hb = lane & 32;
    int c = sub * 8;
    int half = sub >> 4;
    int s0 = rowptr[node], s1 = rowptr[node + 1];
    float acc[8] = {0.f, 0.f, 0.f, 0.f, 0.f, 0.f, 0.f, 0.f};
    for (int base = s0; base < s1; base += 32) {
        int cnt = min(32, s1 - base);
        int idx = 0; float sA = 0.f, sB = 0.f;
        if (sub < cnt) {
            idx = csr_src[base + sub];
            float2 sp = *(const float2*)(hScale + idx * 2);
            sA = sp.x; sB = sp.y;
        }
        int k = 0;
        for (; k + 2 <= cnt; k += 2) {
            int i0 = __shfl(idx, hb + k), i1 = __shfl(idx, hb + k + 1);
            float a0 = __shfl(sA, hb + k), a1 = __shfl(sA, hb + k + 1);
            float b0 = __shfl(sB, hb + k), b1 = __shfl(sB, hb + k + 1);
            float c0 = half ? b0 : a0, c1 = half ? b1 : a1;
            i8x8 v0 = *(const i8x8*)(Hq + (long)i0 * 256 + c);
            i8x8 v1 = *(const i8x8*)(Hq + (long)i1 * 256 + c);
#pragma unroll
            for (int i = 0; i < 8; i++) acc[i] += c0 * (float)v0[i] + c1 * (float)v1[i];
        }
        if (k < cnt) {
            int i0 = __shfl(idx, hb + k);
            float a0 = __shfl(sA, hb + k), b0 = __shfl(sB, hb + k);
            float c0 = half ? b0 : a0;
            i8x8 v0 = *(const i8x8*)(Hq + (long)i0 * 256 + c);
#pragma unroll
            for (int i = 0; i < 8; i++) acc[i] += c0 * (float)v0[i];
        }
    }
    float di = dinv[node];
    bf16x8 o;
#pragma unroll
    for (int i = 0; i < 8; i++) o[i] = (bf16_t)(acc[i] * di);
    *(bf16x8*)(out + (long)node * 256 + c) = o;
}

// ---------- LDS-staged MFMA GEMM: 128x128 tile, BK=64; optional fused int8 quant ----------
template <int KTOT, bool DUAL, bool RELU, bool QUANT>
__global__ __launch_bounds__(256) void gemm_lds(
    const bf16_t* __restrict__ A1, const bf16_t* __restrict__ A2,
    const bf16_t* __restrict__ W1, const bf16_t* __restrict__ W2,
    bf16_t* __restrict__ Out, int N, int NOUT,
    signed char* __restrict__ Hq, float* __restrict__ hScale) {
    __shared__ bf16_t As[128 * 64];
    __shared__ bf16_t Bs[128 * 64];
    __shared__ float sMax[2][2][64];
    int tid = threadIdx.x;
    int w = tid >> 6, lane = tid & 63;
    int wr = w >> 1, wc = w & 1;
    int rowBase = blockIdx.x * 128;
    int colBase = blockIdx.y * 128;
    int m = lane & 15, q = lane >> 4;

    long aoff[4], boff[4];
    int ldsOff[4];
#pragma unroll
    for (int i = 0; i < 4; i++) {
        int c = w * 256 + i * 64 + lane;
        int r = c >> 3, s = c & 7;
        int gk = (s ^ (r & 7)) << 3;
        aoff[i] = (long)min(rowBase + r, N - 1) * KTOT + gk;
        boff[i] = (long)(colBase + r) * KTOT + gk;
        ldsOff[i] = (w * 4 + i) * 512;
    }

    f32x4 acc[4][4];
#pragma unroll
    for (int a = 0; a < 4; a++)
#pragma unroll
        for (int b = 0; b < 4; b++) acc[a][b] = (f32x4){0.f, 0.f, 0.f, 0.f};

#pragma unroll
    for (int half = 0; half < (DUAL ? 2 : 1); half++) {
        const bf16_t* A = half ? A2 : A1;
        const bf16_t* W = half ? W2 : W1;
#pragma unroll
        for (int k0 = 0; k0 < KTOT; k0 += 64) {
            __syncthreads();
#pragma unroll
            for (int i = 0; i < 4; i++) {
                gload_lds16(A + aoff[i] + k0, As + ldsOff[i]);
                gload_lds16(W + boff[i] + k0, Bs + ldsOff[i]);
            }
            __syncthreads();
#pragma unroll
            for (int ks = 0; ks < 2; ks++) {
                bf16x8 af[4], bfr[4];
#pragma unroll
                for (int rf = 0; rf < 4; rf++) {
                    int r = wr * 64 + rf * 16 + m;
                    int seg = ks * 4 + q;
                    af[rf] = *(const bf16x8*)(As + r * 64 + ((seg ^ (r & 7)) << 3));
                }
#pragma unroll
                for (int cf = 0; cf < 4; cf++) {
                    int r = wc * 64 + cf * 16 + m;
                    int seg = ks * 4 + q;
                    bfr[cf] = *(const bf16x8*)(Bs + r * 64 + ((seg ^ (r & 7)) << 3));
                }
#pragma unroll
                for (int rf = 0; rf < 4; rf++)
#pragma unroll
                    for (int cf = 0; cf < 4; cf++)
                        acc[rf][cf] = __builtin_amdgcn_mfma_f32_16x16x32_bf16(af[rf], bfr[cf], acc[rf][cf], 0, 0, 0);
            }
        }
    }

    int r0 = q * 4;
    if constexpr (QUANT) {
        float mm[4][4];
#pragma unroll
        for (int rf = 0; rf < 4; rf++)
#pragma unroll
            for (int i = 0; i < 4; i++) {
                float t = 0.f;
#pragma unroll
                for (int cf = 0; cf < 4; cf++) t = fmaxf(t, fmaxf(acc[rf][cf][i], 0.f));
                mm[rf][i] = t;
            }
#pragma unroll
        for (int o = 1; o < 16; o <<= 1)
#pragma unroll
            for (int rf = 0; rf < 4; rf++)
#pragma unroll
                for (int i = 0; i < 4; i++) mm[rf][i] = fmaxf(mm[rf][i], __shfl_xor(mm[rf][i], o));
        __syncthreads();
        if (m == 0) {
#pragma unroll
            for (int rf = 0; rf < 4; rf++)
#pragma unroll
                for (int i = 0; i < 4; i++) sMax[wr][wc][rf * 16 + q * 4 + i] = mm[rf][i];
        }
        __syncthreads();
#pragma unroll
        for (int rf = 0; rf < 4; rf++) {
#pragma unroll
            for (int i = 0; i < 4; i++) {
                int rowLocal = rf * 16 + r0 + i;
                int row = rowBase + wr * 64 + rowLocal;
                if (row >= N) continue;
                float rm = fmaxf(sMax[wr][0][rowLocal], sMax[wr][1][rowLocal]);
                float rs = rm > 0.f ? 127.f / rm : 0.f;
#pragma unroll
                for (int cf = 0; cf < 4; cf++) {
                    float v = fmaxf(acc[rf][cf][i], 0.f);
                    int col = colBase + wc * 64 + cf * 16 + m;
                    Out[(long)row * NOUT + col] = (bf16_t)v;
                    Hq[(long)row * NOUT + col] =
                        (signed char)fminf(rintf(v * rs), 127.f);
                }
                if (wc == 0 && m == 0)
                    hScale[row * 2 + blockIdx.y] = rm * (1.f / 127.f);
            }
        }
    } else {
#pragma unroll
        for (int rf = 0; rf < 4; rf++) {
#pragma unroll
            for (int i = 0; i < 4; i++) {
                int row = rowBase + wr * 64 + rf * 16 + r0 + i;
                if (row >= N) continue;
#pragma unroll
                for (int cf = 0; cf < 4; cf++) {
                    float v = acc[rf][cf][i];
                    if (RELU) v = fmaxf(v, 0.f);
                    Out[(long)row * NOUT + colBase + wc * 64 + cf * 16 + m] = (bf16_t)v;
                }
            }
        }
    }
}

// ---------- layer-3 GEMM: 96 cols; T3 -> int8 stride-64 + scale, R3 -> bf16 stride-48 ----------
__global__ __launch_bounds__(256) void gemm_mfma3(
    const bf16_t* __restrict__ A1, const bf16_t* __restrict__ W1,
    signed char* __restrict__ T3q, float* __restrict__ t3s,
    bf16_t* __restrict__ R3, int N, int K) {
    const int CF = 3, G = 2;
    int lane = threadIdx.x & 63;
    int wid = blockIdx.x * 4 + (threadIdx.x >> 6);
    int rowTile = wid / G;
    int cg = wid - rowTile * G;
    int rowBase = rowTile * 64;
    if (rowBase >= N) return;
    int colBase = cg * 48;
    int m = lane & 15;
    int kq = (lane >> 4) * 8;

    f32x4 acc[4][CF];
#pragma unroll
    for (int a = 0; a < 4; a++)
#pragma unroll
        for (int b = 0; b < CF; b++) acc[a][b] = (f32x4){0.f, 0.f, 0.f, 0.f};

    long ar[4];
#pragma unroll
    for (int rf = 0; rf < 4; rf++) {
        int r = rowBase + rf * 16 + m;
        ar[rf] = (long)min(r, N - 1) * K;
    }

    for (int k0 = kq; k0 < K; k0 += 32) {
        bf16x8 a[4], b[CF];
#pragma unroll
        for (int rf = 0; rf < 4; rf++) a[rf] = *(const bf16x8*)(A1 + ar[rf] + k0);
#pragma unroll
        for (int cf = 0; cf < CF; cf++)
            b[cf] = *(const bf16x8*)(W1 + (long)(colBase + cf * 16 + m) * K + k0);
#pragma unroll
        for (int rf = 0; rf < 4; rf++)
#pragma unroll
            for (int cf = 0; cf < CF; cf++)
                acc[rf][cf] = __builtin_amdgcn_mfma_f32_16x16x32_bf16(a[rf], b[cf], acc[rf][cf], 0, 0, 0);
    }

    int r0 = (lane >> 4) * 4;
#pragma unroll
    for (int rf = 0; rf < 4; rf++) {
#pragma unroll
        for (int i = 0; i < 4; i++) {
            int row = rowBase + rf * 16 + r0 + i;
            if (cg == 0) {
                float mmx = 0.f;
#pragma unroll
                for (int cf = 0; cf < CF; cf++) mmx = fmaxf(mmx, fabsf(acc[rf][cf][i]));
#pragma unroll
                for (int o = 1; o < 16; o <<= 1) mmx = fmaxf(mmx, __shfl_xor(mmx, o));
                if (row < N) {
                    float rs = mmx > 0.f ? 127.f / mmx : 0.f;
#pragma unroll
                    for (int cf = 0; cf < CF; cf++)
                        T3q[(long)row * 64 + cf * 16 + m] =
                            (signed char)fminf(fmaxf(rintf(acc[rf][cf][i] * rs), -127.f), 127.f);
                    if (m == 0) t3s[row] = mmx * (1.f / 127.f);
                }
            } else if (row < N) {
#pragma unroll
                for (int cf = 0; cf < CF; cf++)
                    R3[(long)row * 48 + cf * 16 + m] = (bf16_t)acc[rf][cf][i];
            }
        }
    }
}

// ---------- final: batched-edge gather of int8 T3 + dinv + R3 + log_softmax ----------
__global__ void final_fused(const int* __restrict__ rowptr, const int* __restrict__ csr_src,
                            const signed char* __restrict__ T3q, const float* __restrict__ t3s,
                            const bf16_t* __restrict__ R3, const float* __restrict__ dinv,
                            float* __restrict__ out, int N) {
    int wid = blockIdx.x * (blockDim.x >> 6) + (threadIdx.x >> 6);
    int lane = threadIdx.x & 63;
    if (wid >= N) return;
    int s0 = rowptr[wid], s1 = rowptr[wid + 1];
    float acc = 0.f;
    for (int base = s0; base < s1; base += 64) {
        int cnt = min(64, s1 - base);
        int idx = 0; float sc = 0.f;
        if (lane < cnt) { idx = csr_src[base + lane]; sc = t3s[idx]; }
        int k = 0;
        for (; k + 4 <= cnt; k += 4) {
            int i0 = __shfl(idx, k), i1 = __shfl(idx, k + 1);
            int i2 = __shfl(idx, k + 2), i3 = __shfl(idx, k + 3);
            float c0 = __shfl(sc, k), c1 = __shfl(sc, k + 1);
            float c2 = __shfl(sc, k + 2), c3 = __shfl(sc, k + 3);
            float v0 = (float)T3q[(long)i0 * 64 + lane];
            float v1 = (float)T3q[(long)i1 * 64 + lane];
            float v2 = (float)T3q[(long)i2 * 64 + lane];
            float v3 = (float)T3q[(long)i3 * 64 + lane];
            acc += c0 * v0 + c1 * v1 + c2 * v2 + c3 * v3;
        }
        for (; k < cnt; k++) {
            int i0 = __shfl(idx, k);
            float c0 = __shfl(sc, k);
            acc += c0 * (float)T3q[(long)i0 * 64 + lane];
        }
    }
    bool act = lane < 47;
    float v = act ? acc * dinv[wid] + (float)R3[(long)wid * 48 + lane] : -INFINITY;
    float mx = v;
#pragma unroll
    for (int o = 32; o; o >>= 1) mx = fmaxf(mx, __shfl_xor(mx, o));
    float ex = act ? expf(v - mx) : 0.f;
    float s = ex;
#pragma unroll
    for (int o = 32; o; o >>= 1) s += __shfl_xor(s, o);
    float ls = logf(s);
    if (act) out[(long)wid * 47 + lane] = v - mx - ls;
}

extern "C" void kernel_launch(void* const* d_in, const int* in_sizes, int n_in,
                              void* d_out, int out_size, void* d_ws, size_t ws_size,
                              hipStream_t stream) {
    const float* x   = (const float*)d_in[0];
    const float* Wl1 = (const float*)d_in[1];
    const float* Wr1 = (const float*)d_in[2];
    const float* Wl2 = (const float*)d_in[3];
    const float* Wr2 = (const float*)d_in[4];
    const float* Wl3 = (const float*)d_in[5];
    const float* Wr3 = (const float*)d_in[6];
    const int*   ei  = (const int*)d_in[7];
    float* out = (float*)d_out;
    const int N = NN, E = NE;
    const int NB = (N + 1023) / 1024;  // 49

    char* ws = (char*)d_ws;
    size_t off = 0;
    auto carve = [&](size_t bytes) { void* p = ws + off; off = (off + bytes + 255) & ~(size_t)255; return p; };
    int*    degi     = (int*)carve((size_t)N * 4);
    int*    rowptr   = (int*)carve((size_t)(N + 1) * 4);
    int*    rank     = (int*)carve((size_t)E * 4);
    int*    csr_src  = (int*)carve((size_t)E * 4);
    int*    partials = (int*)carve(64 * 4);
    float*  dinv     = (float*)carve((size_t)N * 4);
    bf16_t* aggB     = (bf16_t*)carve((size_t)N * 256 * 2);
    bf16_t* xB       = (bf16_t*)carve((size_t)N * 128 * 2);
    signed char* xQ  = (signed char*)carve((size_t)N * 128);
    float*  xScale   = (float*)carve((size_t)N * 4);
    bf16_t* H1       = (bf16_t*)carve((size_t)N * 256 * 2);
    signed char* Hq  = (signed char*)carve((size_t)N * 256);
    float*  hScale   = (float*)carve((size_t)N * 8);   // 2 per row
    bf16_t* H2       = (bf16_t*)carve((size_t)N * 256 * 2);
    bf16_t* wb1l = (bf16_t*)carve(256 * 128 * 2);
    bf16_t* wb1r = (bf16_t*)carve(256 * 128 * 2);
    bf16_t* wb2l = (bf16_t*)carve(256 * 256 * 2);
    bf16_t* wb2r = (bf16_t*)carve(256 * 256 * 2);
    bf16_t* wb3  = (bf16_t*)carve(96 * 256 * 2);
    signed char* T3q = (signed char*)aggB;                                  // N*64 int8
    float*       t3s = (float*)((char*)aggB + (size_t)N * 64);              // N fp32
    bf16_t*      R3  = (bf16_t*)((char*)aggB + (size_t)N * 64 + (size_t)N * 4);  // N*48 bf16

    // --- degi zero + fused converts/deg_count(+rank) ---
    hipMemsetAsync(degi, 0, (size_t)N * 4, stream);
    cvt_all<<<6250 + 216 + 2344, 256, 0, stream>>>(x, xB, xQ, xScale,
                                                   Wl1, Wr1, Wl2, Wr2, Wl3, Wr3,
                                                   wb1l, wb1r, wb2l, wb2r, wb3, ei, degi, rank);

    // --- CSR build (atomic-free fill) ---
    scan_blocks<<<NB, 1024, 0, stream>>>(degi, rowptr, dinv, partials, N);
    add_offsets<<<(N + 255) / 256, 256, 0, stream>>>(rowptr, partials, NB, N);
    fill_csr<<<(E / 2 + 255) / 256, 256, 0, stream>>>(ei, rank, rowptr, csr_src, E);

    const int RT = (N + 127) / 128;  // 391

    // --- layer 1 (int8 gather; GEMM fuses H1 int8 quant) ---
    gather_agg_128<<<(N / 2 + 3) / 4, 256, 0, stream>>>(rowptr, csr_src, xQ, xScale, dinv, aggB, N);
    gemm_lds<128, true, true, true><<<dim3(RT, 2), 256, 0, stream>>>(
        aggB, xB, wb1l, wb1r, H1, N, 256, Hq, hScale);

    // --- layer 2 ---
    gather_agg_256<<<(N / 2 + 3) / 4, 256, 0, stream>>>(rowptr, csr_src, Hq, hScale, dinv, aggB, N);
    gemm_lds<256, true, true, false><<<dim3(RT, 2), 256, 0, stream>>>(
        aggB, H1, wb2l, wb2r, H2, N, 256, nullptr, nullptr);

    // --- layer 3 (T3 int8 fused) + fused gather/log_softmax ---
    gemm_mfma3<<<391, 256, 0, stream>>>(H2, wb3, T3q, t3s, R3, N, 256);
    final_fused<<<(N + 3) / 4, 256, 0, stream>>>(rowptr, csr_src, T3q, t3s, R3, dinv, out, N);
}